// Round 9
// baseline (110.942 us; speedup 1.0000x reference)
//
#include <hip/hip_runtime.h>
#include <hip/hip_bf16.h>

// Problem dims: x[b=8, c=64, h=64, w=64, t=12] fp32
// x float offsets: b*3145728 + c*49152 + h*768 + w*12 + t
//
// Scratch inside d_out (floats), consumed before k_out overwrites d_out:
//   [0,1600)           : Weff[c*25 + tap],  tap = dh*5+dw
//   [4096, 4096+9.83M) : y[tap][m*12+t], m = (b*64+h)*64+w   (25 planes, 39.3 MB)
#define WEFF_OFF 0
#define Y_OFF    4096
#define Y_PLANE  393216   // floats per tap plane
// d_ws: p[m*12 + t]  (1.57 MB)

// ---------------------------------------------------------------------------
// K1: fold 1x1-conv (key half of w1) into the 5x5 conv weights.
__global__ __launch_bounds__(256) void k_prep(const float* __restrict__ w1,
                                              const float* __restrict__ w2,
                                              float* __restrict__ weff) {
    int idx = blockIdx.x * 256 + threadIdx.x;
    if (idx >= 64 * 25) return;
    int cp = idx / 25, tap = idx % 25;
    float s = 0.f;
    for (int c = 0; c < 64; ++c)
        s = fmaf(w2[(64 + c) * 25 + tap], w1[(64 + c) * 64 + cp], s);
    weff[cp * 25 + tap] = s;
}

// ---------------------------------------------------------------------------
// K2a (k_tap v4): per-tap channel contraction, in-flight-maximized.
// Thread per (m, t-quad): n = m*3+tg; lane addr = 16B*n + const => 1KB/wave
// coalesced float4 per channel. Channel loop = two 32-deep batches: 32
// independent global_load_dwordx4 in flight (32KB/wave; R8's invariant
// ~12KB/SIMD -> now ~48KB/SIMD), then 32x100 FMA. VGPR ~240 (<450, no
// spill; occupancy is thread-limited so VGPR free). 768 blocks x 128 thr
// = 3 blocks/CU exact. x read exactly once; y written once.
__global__ __launch_bounds__(128) void k_tap(const float* __restrict__ x,
                                             const float* __restrict__ weff,
                                             float* __restrict__ y) {
    const int n  = blockIdx.x * 128 + threadIdx.x;   // 0..98303 = m*3+tg
    const int m  = n / 3;
    const int b  = m >> 12;                          // block-uniform (12288%128==0)

    // float index: b*3096576 + n*4 (+ c*49152)
    const float* xp = x + (size_t)b * 3096576 + (size_t)n * 4;

    float4 acc[25];
#pragma unroll
    for (int k = 0; k < 25; ++k) { acc[k].x = 0.f; acc[k].y = 0.f; acc[k].z = 0.f; acc[k].w = 0.f; }

#pragma unroll
    for (int half = 0; half < 2; ++half) {
        const float* xh = xp + (size_t)(half * 32) * 49152;
        float4 v[32];
#pragma unroll
        for (int j = 0; j < 32; ++j)
            v[j] = *(const float4*)(xh + (size_t)j * 49152);   // 32 loads in flight
#pragma unroll
        for (int j = 0; j < 32; ++j) {
            const float* wg = weff + (half * 32 + j) * 25;     // wave-uniform -> s_loads
#pragma unroll
            for (int k = 0; k < 25; ++k) {
                const float g = wg[k];
                acc[k].x = fmaf(g, v[j].x, acc[k].x);
                acc[k].y = fmaf(g, v[j].y, acc[k].y);
                acc[k].z = fmaf(g, v[j].z, acc[k].z);
                acc[k].w = fmaf(g, v[j].w, acc[k].w);
            }
        }
    }

#pragma unroll
    for (int k = 0; k < 25; ++k)
        *(float4*)(y + (size_t)k * Y_PLANE + (size_t)n * 4) = acc[k];
}

// ---------------------------------------------------------------------------
// K2b (k_gather v2): A_k[m,t] = sum_taps y[tap][shifted m, t] (OOB skipped ==
// zero-pad), softmax over t, write p. Lane-quad per m: q=0..2 own t-quads,
// lane 3 duplicates lane 2. 131,072 threads = 8 waves/CU; y is L3-resident.
__global__ __launch_bounds__(256) void k_gather(const float* __restrict__ y,
                                                float* __restrict__ p) {
    const int tid  = threadIdx.x;
    const int m    = blockIdx.x * 64 + (tid >> 2);   // 0..32767
    const int q    = tid & 3;
    const int qq   = (q == 3) ? 2 : q;               // lane3 mirrors lane2
    const int w    = m & 63;
    const int h    = (m >> 6) & 63;
    const int b    = m >> 12;

    float4 a; a.x = 0.f; a.y = 0.f; a.z = 0.f; a.w = 0.f;

#pragma unroll
    for (int dh = 0; dh < 5; ++dh) {
        const int hh = h + dh - 2;
        if ((unsigned)hh >= 64u) continue;           // block-uniform skip
        const int rowb = (b * 64 + hh) * 64;
#pragma unroll
        for (int dw = 0; dw < 5; ++dw) {
            const int ww = w + dw - 2;
            if ((unsigned)ww >= 64u) continue;       // edge lanes only
            const float* yp = y + (size_t)(dh * 5 + dw) * Y_PLANE
                                + (size_t)(rowb + ww) * 12 + qq * 4;
            float4 v = *(const float4*)(yp);
            a.x += v.x; a.y += v.y; a.z += v.z; a.w += v.w;
        }
    }

    // softmax over 12 t across lanes q=0..2 of the quad
    float mx = fmaxf(fmaxf(a.x, a.y), fmaxf(a.z, a.w));
    mx = fmaxf(mx, __shfl_xor(mx, 1, 4));
    mx = fmaxf(mx, __shfl_xor(mx, 2, 4));   // lane3 dup is idempotent for max

    float e0 = __expf(a.x - mx), e1 = __expf(a.y - mx);
    float e2 = __expf(a.z - mx), e3 = __expf(a.w - mx);
    const float s4 = e0 + e1 + e2 + e3;
    const float s0 = __shfl(s4, 0, 4);
    const float s1 = __shfl(s4, 1, 4);
    const float s2 = __shfl(s4, 2, 4);
    const float inv = 1.f / (s0 + s1 + s2);

    if (q < 3) {
        float4 o; o.x = e0 * inv; o.y = e1 * inv; o.z = e2 * inv; o.w = e3 * inv;
        *(float4*)(p + (size_t)m * 12 + q * 4) = o;
    }
}

// ---------------------------------------------------------------------------
// K4: out[b,c,h,w,s] = W1v · (sum_t p_t * x[:,t]) + b1v, broadcast over s.
// One block per (b,h): 512 threads = 64 w-lanes * 8 channel-groups.
__global__ __launch_bounds__(512) void k_out(const float* __restrict__ x,
                                             const float* __restrict__ w1,
                                             const float* __restrict__ b1,
                                             const float* __restrict__ p,
                                             float* __restrict__ out) {
    __shared__ float lds[64 * 65];   // [w][c], padded -> conflict-free

    const int b  = blockIdx.x >> 6;
    const int h  = blockIdx.x & 63;
    const int w  = threadIdx.x & 63;
    const int cg = threadIdx.x >> 6;     // 0..7

    const float* pp = p + (size_t)((b * 64 + h) * 64 + w) * 12;
    float pv[12];
    {
        float4 t0 = *(const float4*)(pp);
        float4 t1 = *(const float4*)(pp + 4);
        float4 t2 = *(const float4*)(pp + 8);
        pv[0] = t0.x; pv[1] = t0.y; pv[2]  = t0.z; pv[3]  = t0.w;
        pv[4] = t1.x; pv[5] = t1.y; pv[6]  = t1.z; pv[7]  = t1.w;
        pv[8] = t2.x; pv[9] = t2.y; pv[10] = t2.z; pv[11] = t2.w;
    }

    const float* xb0 = x + ((size_t)(b * 64 + cg * 8) * 64 + h) * 768 + w * 12;
#pragma unroll
    for (int j = 0; j < 8; ++j) {
        const float* xp = xb0 + (size_t)j * 49152;
        float4 u0 = *(const float4*)(xp);
        float4 u1 = *(const float4*)(xp + 4);
        float4 u2 = *(const float4*)(xp + 8);
        float s = 0.f;
        s = fmaf(pv[0], u0.x, s);  s = fmaf(pv[1], u0.y, s);
        s = fmaf(pv[2], u0.z, s);  s = fmaf(pv[3], u0.w, s);
        s = fmaf(pv[4], u1.x, s);  s = fmaf(pv[5], u1.y, s);
        s = fmaf(pv[6], u1.z, s);  s = fmaf(pv[7], u1.w, s);
        s = fmaf(pv[8], u2.x, s);  s = fmaf(pv[9], u2.y, s);
        s = fmaf(pv[10], u2.z, s); s = fmaf(pv[11], u2.w, s);
        lds[w * 65 + cg * 8 + j] = s;
    }
    __syncthreads();

    const float* w1v = w1 + 128 * 64 + cg * 8 * 64;
    float acc[8];
#pragma unroll
    for (int j = 0; j < 8; ++j) acc[j] = b1[128 + cg * 8 + j];
    for (int c2 = 0; c2 < 64; ++c2) {
        const float xv = lds[w * 65 + c2];
#pragma unroll
        for (int j = 0; j < 8; ++j)
            acc[j] = fmaf(w1v[j * 64 + c2], xv, acc[j]);
    }

#pragma unroll
    for (int j = 0; j < 8; ++j) {
        const int co = cg * 8 + j;
        float4 f; f.x = acc[j]; f.y = acc[j]; f.z = acc[j]; f.w = acc[j];
        float* op = out + ((size_t)(b * 64 + co) * 4096 + h * 64 + w) * 12;
        *(float4*)(op)     = f;
        *(float4*)(op + 4) = f;
        *(float4*)(op + 8) = f;
    }
}

// ---------------------------------------------------------------------------
extern "C" void kernel_launch(void* const* d_in, const int* in_sizes, int n_in,
                              void* d_out, int out_size, void* d_ws, size_t ws_size,
                              hipStream_t stream) {
    const float* x  = (const float*)d_in[0];
    const float* w1 = (const float*)d_in[1];
    const float* b1 = (const float*)d_in[2];
    const float* w2 = (const float*)d_in[3];
    // d_in[4] = b2: constant across the softmax axis -> cancels, unused.

    float* outp = (float*)d_out;
    float* weff = outp + WEFF_OFF;
    float* y    = outp + Y_OFF;      // 39.3 MB tap planes (scratch in d_out)
    float* p    = (float*)d_ws;      // 1.57 MB

    hipLaunchKernelGGL(k_prep,   dim3(7),    dim3(256), 0, stream, w1, w2, weff);
    hipLaunchKernelGGL(k_tap,    dim3(768),  dim3(128), 0, stream, x, weff, y);
    hipLaunchKernelGGL(k_gather, dim3(512),  dim3(256), 0, stream, y, p);
    hipLaunchKernelGGL(k_out,    dim3(512),  dim3(512), 0, stream, x, w1, b1, p, outp);
}

// Round 10
// 96.316 us; speedup vs baseline: 1.1519x; 1.1519x over previous
//
#include <hip/hip_runtime.h>
#include <hip/hip_bf16.h>

// Problem dims: x[b=8, c=64, h=64, w=64, t=12] fp32
// x float offsets: b*3145728 + c*49152 + h*768 + w*12 + t
//
// Scratch inside d_out (floats): [0,1600) = Weff[c*25 + tap], tap = dh*5+dw
// (read by k_conv5 before k_out overwrites d_out)
#define WEFF_OFF 0
// d_ws: p[m*12 + t], m = (b*64+h)*64+w   (1.57 MB)

// ---------------------------------------------------------------------------
// K1: fold 1x1-conv (key half of w1) into the 5x5 conv weights.
__global__ __launch_bounds__(256) void k_prep(const float* __restrict__ w1,
                                              const float* __restrict__ w2,
                                              float* __restrict__ weff) {
    int idx = blockIdx.x * 256 + threadIdx.x;
    if (idx >= 64 * 25) return;
    int cp = idx / 25, tap = idx % 25;
    float s = 0.f;
    for (int c = 0; c < 64; ++c)
        s = fmaf(w2[(64 + c) * 25 + tap], w1[(64 + c) * 64 + cp], s);
    weff[cp * 25 + tap] = s;
}

// ---------------------------------------------------------------------------
// K2 (k_conv5): fused conv + softmax, built from k_out's proven read shape.
// Block = (b,h) output row; 320 thr = 64 w-lanes x 5 dh-waves. Thread (w,dh)
// reads input row r=h+dh-2, ALL 64 channels, as contiguous 48B (w,12t)
// columns (k_out pattern), FMAs into zz[dw][t] with 5 wave-uniform weights
// per channel. Deterministic 5-turn LDS reduction scatters to output cols
// w' = w+2-dw; wave 0 sums dw, softmaxes over t, writes p. No y scratch.
// Grid XCD-swizzled: bid%8=XCD gets b=bid&7 contiguous-h chunk -> h-neighbor
// row reuse hits the same XCD's L2.
__global__ __launch_bounds__(320) void k_conv5(const float* __restrict__ x,
                                               const float* __restrict__ weff,
                                               float* __restrict__ p) {
    __shared__ float lds[64 * 61];   // [w'][dw*12+t], stride 61 (odd) -> conflict-free

    const int bid = blockIdx.x;      // 512 = 8 XCD-chunks x 64
    const int b   = bid & 7;         // XCD id -> fixed b per XCD
    const int h   = bid >> 3;        // contiguous h within XCD
    const int w   = threadIdx.x & 63;
    const int dh  = threadIdx.x >> 6;    // 0..4 (wave id)
    const int r   = h + dh - 2;

    // zero the accumulator LDS
    for (int i = threadIdx.x; i < 64 * 61; i += 320) lds[i] = 0.f;

    float zz[5][12];
#pragma unroll
    for (int dw = 0; dw < 5; ++dw)
#pragma unroll
        for (int t = 0; t < 12; ++t) zz[dw][t] = 0.f;

    if ((unsigned)r < 64u) {
        const float* xp = x + (size_t)b * 3145728 + r * 768 + w * 12;
        const float* wgb = weff + dh * 5;    // wave-uniform
        for (int c = 0; c < 64; c += 2) {
            const float* x0 = xp + (size_t)c * 49152;
            const float* x1 = x0 + 49152;
            float4 a0 = *(const float4*)(x0);
            float4 a1 = *(const float4*)(x0 + 4);
            float4 a2 = *(const float4*)(x0 + 8);
            float4 c0 = *(const float4*)(x1);
            float4 c1 = *(const float4*)(x1 + 4);
            float4 c2 = *(const float4*)(x1 + 8);
            const float* wg0 = wgb + c * 25;
            const float* wg1 = wg0 + 25;
#pragma unroll
            for (int dw = 0; dw < 5; ++dw) {
                const float g = wg0[dw];
                zz[dw][0] = fmaf(g, a0.x, zz[dw][0]);  zz[dw][1] = fmaf(g, a0.y, zz[dw][1]);
                zz[dw][2] = fmaf(g, a0.z, zz[dw][2]);  zz[dw][3] = fmaf(g, a0.w, zz[dw][3]);
                zz[dw][4] = fmaf(g, a1.x, zz[dw][4]);  zz[dw][5] = fmaf(g, a1.y, zz[dw][5]);
                zz[dw][6] = fmaf(g, a1.z, zz[dw][6]);  zz[dw][7] = fmaf(g, a1.w, zz[dw][7]);
                zz[dw][8] = fmaf(g, a2.x, zz[dw][8]);  zz[dw][9] = fmaf(g, a2.y, zz[dw][9]);
                zz[dw][10] = fmaf(g, a2.z, zz[dw][10]); zz[dw][11] = fmaf(g, a2.w, zz[dw][11]);
            }
#pragma unroll
            for (int dw = 0; dw < 5; ++dw) {
                const float g = wg1[dw];
                zz[dw][0] = fmaf(g, c0.x, zz[dw][0]);  zz[dw][1] = fmaf(g, c0.y, zz[dw][1]);
                zz[dw][2] = fmaf(g, c0.z, zz[dw][2]);  zz[dw][3] = fmaf(g, c0.w, zz[dw][3]);
                zz[dw][4] = fmaf(g, c1.x, zz[dw][4]);  zz[dw][5] = fmaf(g, c1.y, zz[dw][5]);
                zz[dw][6] = fmaf(g, c1.z, zz[dw][6]);  zz[dw][7] = fmaf(g, c1.w, zz[dw][7]);
                zz[dw][8] = fmaf(g, c2.x, zz[dw][8]);  zz[dw][9] = fmaf(g, c2.y, zz[dw][9]);
                zz[dw][10] = fmaf(g, c2.z, zz[dw][10]); zz[dw][11] = fmaf(g, c2.w, zz[dw][11]);
            }
        }
    }
    __syncthreads();

    // deterministic 5-turn cross-wave accumulation: thread's input col w
    // contributes to output col w' = w+2-dw
#pragma unroll
    for (int turn = 0; turn < 5; ++turn) {
        if (dh == turn) {
#pragma unroll
            for (int dw = 0; dw < 5; ++dw) {
                const int wp = w + 2 - dw;
                if ((unsigned)wp < 64u) {
                    float* a = lds + wp * 61 + dw * 12;
#pragma unroll
                    for (int t = 0; t < 12; ++t) a[t] += zz[dw][t];
                }
            }
        }
        __syncthreads();
    }

    // wave 0: sum dw, softmax over t, write p
    if (dh == 0) {
        const float* lw = lds + w * 61;
        float v[12];
#pragma unroll
        for (int t = 0; t < 12; ++t)
            v[t] = lw[t] + lw[12 + t] + lw[24 + t] + lw[36 + t] + lw[48 + t];
        float mx = v[0];
#pragma unroll
        for (int t = 1; t < 12; ++t) mx = fmaxf(mx, v[t]);
        float s = 0.f;
#pragma unroll
        for (int t = 0; t < 12; ++t) { v[t] = __expf(v[t] - mx); s += v[t]; }
        const float inv = 1.f / s;
#pragma unroll
        for (int t = 0; t < 12; ++t) v[t] *= inv;
        float* op = p + (size_t)((b * 64 + h) * 64 + w) * 12;
        float4 s0; s0.x = v[0]; s0.y = v[1]; s0.z = v[2];  s0.w = v[3];
        float4 s1; s1.x = v[4]; s1.y = v[5]; s1.z = v[6];  s1.w = v[7];
        float4 s2; s2.x = v[8]; s2.y = v[9]; s2.z = v[10]; s2.w = v[11];
        *(float4*)(op)     = s0;
        *(float4*)(op + 4) = s1;
        *(float4*)(op + 8) = s2;
    }
}

// ---------------------------------------------------------------------------
// K4: out[b,c,h,w,s] = W1v · (sum_t p_t * x[:,t]) + b1v, broadcast over s.
// One block per (b,h): 512 threads = 64 w-lanes * 8 channel-groups.
__global__ __launch_bounds__(512) void k_out(const float* __restrict__ x,
                                             const float* __restrict__ w1,
                                             const float* __restrict__ b1,
                                             const float* __restrict__ p,
                                             float* __restrict__ out) {
    __shared__ float lds[64 * 65];   // [w][c], padded -> conflict-free

    const int b  = blockIdx.x >> 6;
    const int h  = blockIdx.x & 63;
    const int w  = threadIdx.x & 63;
    const int cg = threadIdx.x >> 6;     // 0..7

    const float* pp = p + (size_t)((b * 64 + h) * 64 + w) * 12;
    float pv[12];
    {
        float4 t0 = *(const float4*)(pp);
        float4 t1 = *(const float4*)(pp + 4);
        float4 t2 = *(const float4*)(pp + 8);
        pv[0] = t0.x; pv[1] = t0.y; pv[2]  = t0.z; pv[3]  = t0.w;
        pv[4] = t1.x; pv[5] = t1.y; pv[6]  = t1.z; pv[7]  = t1.w;
        pv[8] = t2.x; pv[9] = t2.y; pv[10] = t2.z; pv[11] = t2.w;
    }

    const float* xb0 = x + ((size_t)(b * 64 + cg * 8) * 64 + h) * 768 + w * 12;
#pragma unroll
    for (int j = 0; j < 8; ++j) {
        const float* xp = xb0 + (size_t)j * 49152;
        float4 u0 = *(const float4*)(xp);
        float4 u1 = *(const float4*)(xp + 4);
        float4 u2 = *(const float4*)(xp + 8);
        float s = 0.f;
        s = fmaf(pv[0], u0.x, s);  s = fmaf(pv[1], u0.y, s);
        s = fmaf(pv[2], u0.z, s);  s = fmaf(pv[3], u0.w, s);
        s = fmaf(pv[4], u1.x, s);  s = fmaf(pv[5], u1.y, s);
        s = fmaf(pv[6], u1.z, s);  s = fmaf(pv[7], u1.w, s);
        s = fmaf(pv[8], u2.x, s);  s = fmaf(pv[9], u2.y, s);
        s = fmaf(pv[10], u2.z, s); s = fmaf(pv[11], u2.w, s);
        lds[w * 65 + cg * 8 + j] = s;
    }
    __syncthreads();

    const float* w1v = w1 + 128 * 64 + cg * 8 * 64;
    float acc[8];
#pragma unroll
    for (int j = 0; j < 8; ++j) acc[j] = b1[128 + cg * 8 + j];
    for (int c2 = 0; c2 < 64; ++c2) {
        const float xv = lds[w * 65 + c2];
#pragma unroll
        for (int j = 0; j < 8; ++j)
            acc[j] = fmaf(w1v[j * 64 + c2], xv, acc[j]);
    }

#pragma unroll
    for (int j = 0; j < 8; ++j) {
        const int co = cg * 8 + j;
        float4 f; f.x = acc[j]; f.y = acc[j]; f.z = acc[j]; f.w = acc[j];
        float* op = out + ((size_t)(b * 64 + co) * 4096 + h * 64 + w) * 12;
        *(float4*)(op)     = f;
        *(float4*)(op + 4) = f;
        *(float4*)(op + 8) = f;
    }
}

// ---------------------------------------------------------------------------
extern "C" void kernel_launch(void* const* d_in, const int* in_sizes, int n_in,
                              void* d_out, int out_size, void* d_ws, size_t ws_size,
                              hipStream_t stream) {
    const float* x  = (const float*)d_in[0];
    const float* w1 = (const float*)d_in[1];
    const float* b1 = (const float*)d_in[2];
    const float* w2 = (const float*)d_in[3];
    // d_in[4] = b2: constant across the softmax axis -> cancels, unused.

    float* outp = (float*)d_out;
    float* weff = outp + WEFF_OFF;   // 6.4 KB scratch in d_out, read before k_out
    float* p    = (float*)d_ws;      // 1.57 MB

    hipLaunchKernelGGL(k_prep,  dim3(7),   dim3(256), 0, stream, w1, w2, weff);
    hipLaunchKernelGGL(k_conv5, dim3(512), dim3(320), 0, stream, x, weff, p);
    hipLaunchKernelGGL(k_out,   dim3(512), dim3(512), 0, stream, x, w1, b1, p, outp);
}